// Round 15
// baseline (385.731 us; speedup 1.0000x reference)
//
#include <hip/hip_runtime.h>
#include <hip/hip_bf16.h>
#include <hip/hip_cooperative_groups.h>
#include <math.h>

namespace cg = cooperative_groups;

// ---------------------------------------------------------------------------
// FeatureNet (DGCNN edge-conv block), MI355X / gfx950, round 15.
//
// Round-15: cooperative mega-kernel retried with both r14 failure modes fixed:
//  * stats reads after grid.sync use __hip_atomic_load (AGENT scope) --
//    plain loads may serve stale per-XCD L2 lines (G16 boundary).
//  * hipLaunchCooperativeKernel return code checked; on failure fall back to
//    the r13-proven conv2stats+convfused pipeline (correct at 206us).
// kNN / finalize1 / fallback kernels = r13-proven.
// ---------------------------------------------------------------------------

#define B_   16
#define N_   2048
#define KNN  8
#define DIM  128
#define P_   (B_*N_*KNN)   // 262144
#define CAP  128
#define NBLK 2048          // conv tiles (128 p each)
#define MGRID 512          // mega blocks (4 tiles each)

typedef __attribute__((ext_vector_type(8))) short bf16x8;
typedef __attribute__((ext_vector_type(4))) short bf16x4;
typedef __attribute__((ext_vector_type(4))) float f32x4;

// ws layout (bytes)
#define OFF_G     0ull
#define SZ_G      ((size_t)P_*16)
#define OFF_STATS (OFF_G + SZ_G)
#define N_STATS   4112
#define SZ_STATS  ((size_t)N_STATS*8)
#define OFF_AB    (OFF_STATS + SZ_STATS)
#define SZ_AB     4096ull
#define OFF_KPART (OFF_AB + SZ_AB)
#define NKBLK     2048
#define SZ_KPART  ((size_t)9*NKBLK*4)
#define OFF_YMM   (OFF_KPART + SZ_KPART)
#define SZ_YMM    ((size_t)DIM*NBLK*32*4)

// stats (f64) indices
#define I_S2   16
#define I_S3   (16 + 8*256)
#define NBANK  8

// ab (float) layout
#define AB_W1F 0
#define AB_A2  512
#define AB_E2  640
#define AB_A3  768
#define AB_E3  896

// DPP ctrl codes
#define DPP_XOR1   0xB1
#define DPP_XOR2   0x4E
#define DPP_HALFM  0x141
#define DPP_MIRROR 0x140

template<int C>
__device__ __forceinline__ float dppf(float v) {
    return __int_as_float(__builtin_amdgcn_update_dpp(
        __float_as_int(v), __float_as_int(v), C, 0xF, 0xF, false));
}

__device__ __forceinline__ void atomAddD(double* p, double v) {
    __hip_atomic_fetch_add(p, v, __ATOMIC_RELAXED, __HIP_MEMORY_SCOPE_AGENT);
}
__device__ __forceinline__ double aloadD(const double* p) {
    return __hip_atomic_load(p, __ATOMIC_RELAXED, __HIP_MEMORY_SCOPE_AGENT);
}
__device__ __forceinline__ unsigned short f2bs(float f) {
    const unsigned b = __float_as_uint(f);
    return (unsigned short)((b + 0x7FFFu + ((b >> 16) & 1u)) >> 16);   // RNE
}
__device__ __forceinline__ float bs2f(unsigned short u) {
    return __uint_as_float(((unsigned)u) << 16);
}

// ---------------------------------------------------------------------------
// kNN + grouped offsets + layer-1 moment partials + stats zeroing (r13 proven).
__global__ __launch_bounds__(1024) void knn_group_kernel(
    const float* __restrict__ x, float4* __restrict__ g4,
    float* __restrict__ kpart, double* __restrict__ st)
{
    __shared__ __align__(16) float4 xs4[N_];
    __shared__ unsigned long long listK[16][CAP];
    __shared__ float spart[16][12];
    const int b   = blockIdx.y;
    const int tid = threadIdx.x;
    const int wv  = tid >> 6;
    const int ln  = tid & 63;
    const int n   = blockIdx.x * 16 + wv;
    const float* xb = x + (size_t)b * 3 * N_;

    if (blockIdx.x == 0 && blockIdx.y == 0)
        for (int i = tid; i < N_STATS; i += 1024) st[i] = 0.0;

    for (int i = tid; i < N_; i += 1024) {
        const float a0 = xb[i], a1 = xb[N_ + i], a2 = xb[2*N_ + i];
        const float sq = __fadd_rn(__fadd_rn(__fmul_rn(a0,a0), __fmul_rn(a1,a1)), __fmul_rn(a2,a2));
        xs4[i] = make_float4(a0, a1, a2, sq);
    }
    __syncthreads();

    const float4 me = xs4[n];
    const float xn0 = me.x, xn1 = me.y, xn2 = me.z, sqn = me.w;

    float dreg[32];
    float lmin = INFINITY;
    #pragma unroll
    for (int i = 0; i < 32; ++i) {
        const float4 q = xs4[ln + 64*i];
        dreg[i] = __fadd_rn(__fmaf_rn(-2.f, __fmaf_rn(xn2, q.z, __fmaf_rn(xn1, q.y, __fmul_rn(xn0, q.x))), sqn), q.w);
        lmin = fminf(lmin, dreg[i]);
    }

    float gm = lmin;
    gm = fminf(gm, __shfl_xor(gm, 1));
    gm = fminf(gm, __shfl_xor(gm, 2));
    gm = fminf(gm, __shfl_xor(gm, 4));
    float Bb = gm;
    Bb = fmaxf(Bb, __shfl_xor(Bb, 8));
    Bb = fmaxf(Bb, __shfl_xor(Bb, 16));
    Bb = fmaxf(Bb, __shfl_xor(Bb, 32));

    unsigned base = 0;
    #pragma unroll
    for (int i = 0; i < 32; ++i) {
        const bool pred = (dreg[i] <= Bb);
        const unsigned long long mk = __ballot(pred);
        if (pred) {
            const unsigned pos = base + (unsigned)__popcll(mk & ((1ull << ln) - 1ull));
            if (pos < CAP) {
                const unsigned u = __float_as_uint(dreg[i]);
                const unsigned od = u ^ ((unsigned)(((int)u) >> 31) | 0x80000000u);
                listK[wv][pos] = (((unsigned long long)od) << 32) | (unsigned)(ln + 64*i);
            }
        }
        base += (unsigned)__popcll(mk);
    }
    const int cnt = (base < CAP) ? (int)base : CAP;

    int myi = 0;
    if (cnt <= 64) {
        unsigned long long K = (ln < cnt) ? listK[wv][ln] : ~0ull;
        #pragma unroll
        for (int k = 2; k <= 64; k <<= 1) {
            #pragma unroll
            for (int j = k >> 1; j >= 1; j >>= 1) {
                const unsigned long long o = __shfl_xor(K, j);
                const bool takeMin = (((ln & j) == 0) == ((ln & k) == 0));
                const bool oLess = (o < K);
                if (takeMin ? oLess : !oLess) K = o;
            }
        }
        myi = (int)(unsigned)K;
    } else {
        unsigned long long K0 = (ln < cnt)      ? listK[wv][ln]      : ~0ull;
        unsigned long long K1 = (ln + 64 < cnt) ? listK[wv][ln + 64] : ~0ull;
        #pragma unroll
        for (int sel = 0; sel < 8; ++sel) {
            unsigned long long p = (K1 < K0) ? K1 : K0;
            #pragma unroll
            for (int m = 1; m < 64; m <<= 1) {
                const unsigned long long o = __shfl_xor(p, m);
                if (o < p) p = o;
            }
            if (ln == sel) myi = (int)(unsigned)p;
            if (K0 == p) K0 = ~0ull;
            if (K1 == p) K1 = ~0ull;
        }
    }

    if (ln < 8) {
        const float4 q = xs4[myi];
        const float g0  = q.x - xn0;
        const float g1v = q.y - xn1;
        const float g2v = q.z - xn2;
        g4[((size_t)b*N_ + n)*KNN + ln] = make_float4(g0, g1v, g2v, 0.f);
        float s0 = g0, s1 = g1v, s2 = g2v;
        float s00 = g0*g0, s01 = g0*g1v, s02 = g0*g2v;
        float s11 = g1v*g1v, s12 = g1v*g2v, s22 = g2v*g2v;
        #pragma unroll
        for (int m = 1; m < 8; m <<= 1) {
            s0 += __shfl_xor(s0, m);  s1 += __shfl_xor(s1, m);  s2 += __shfl_xor(s2, m);
            s00 += __shfl_xor(s00, m); s01 += __shfl_xor(s01, m); s02 += __shfl_xor(s02, m);
            s11 += __shfl_xor(s11, m); s12 += __shfl_xor(s12, m); s22 += __shfl_xor(s22, m);
        }
        if (ln == 0) {
            spart[wv][0] = s0;  spart[wv][1] = s1;  spart[wv][2] = s2;
            spart[wv][3] = s00; spart[wv][4] = s01; spart[wv][5] = s02;
            spart[wv][6] = s11; spart[wv][7] = s12; spart[wv][8] = s22;
        }
    }
    __syncthreads();
    if (tid < 9) {
        float a = 0.f;
        #pragma unroll
        for (int w = 0; w < 16; ++w) a += spart[w][tid];
        kpart[tid*NKBLK + blockIdx.y*128 + blockIdx.x] = a;
    }
}

// ---------------------------------------------------------------------------
__global__ __launch_bounds__(1024) void finalize1_kernel(
    const float* __restrict__ kpart, const float* __restrict__ W1,
    const float* __restrict__ b1, const float* __restrict__ g1,
    const float* __restrict__ be1, float* __restrict__ ab)
{
    __shared__ double S9[9];
    const int tid = threadIdx.x;
    const int w = tid >> 6, l = tid & 63;
    if (w < 9) {
        double a = 0.0;
        #pragma unroll
        for (int i = 0; i < 32; ++i) a += (double)kpart[w*NKBLK + l + 64*i];
        #pragma unroll
        for (int m = 1; m < 64; m <<= 1) a += __shfl_xor(a, m);
        if (l == 0) S9[w] = a;
    }
    __syncthreads();
    if (tid < 128) {
        const int d = tid;
        const double inv = 1.0 / (double)P_;
        const double mu0 = S9[0]*inv, mu1 = S9[1]*inv, mu2 = S9[2]*inv;
        const double c00 = S9[3]*inv - mu0*mu0;
        const double c01 = S9[4]*inv - mu0*mu1;
        const double c02 = S9[5]*inv - mu0*mu2;
        const double c11 = S9[6]*inv - mu1*mu1;
        const double c12 = S9[7]*inv - mu1*mu2;
        const double c22 = S9[8]*inv - mu2*mu2;
        const double w0 = W1[d*3+0], w1 = W1[d*3+1], w2 = W1[d*3+2];
        const double mean = w0*mu0 + w1*mu1 + w2*mu2 + (double)b1[d];
        double var = w0*w0*c00 + w1*w1*c11 + w2*w2*c22
                   + 2.0*(w0*w1*c01 + w0*w2*c02 + w1*w2*c12);
        if (var < 0.0) var = 0.0;
        const double r = 1.0 / sqrt(var + 1e-5);
        const double alpha = (double)g1[d] * r;
        const double beta  = (double)be1[d] - mean*alpha;
        ab[AB_W1F + 4*d + 0] = (float)(alpha * w0);
        ab[AB_W1F + 4*d + 1] = (float)(alpha * w1);
        ab[AB_W1F + 4*d + 2] = (float)(alpha * w2);
        ab[AB_W1F + 4*d + 3] = (float)(alpha * (double)b1[d] + beta);
    }
}

__global__ void finalize23_kernel(
    const double* __restrict__ st, int soff,
    const float* __restrict__ gg, const float* __restrict__ bee,
    float* __restrict__ ab, int aoff)
{
    const int d = threadIdx.x;
    if (d >= DIM) return;
    double s1 = 0.0, s2 = 0.0;
    #pragma unroll
    for (int k = 0; k < NBANK; ++k) {
        s1 += st[soff + k*256 + d];
        s2 += st[soff + k*256 + 128 + d];
    }
    const double inv = 1.0 / (double)P_;
    const double mean = s1 * inv;
    double var = s2 * inv - mean*mean;
    if (var < 0.0) var = 0.0;
    const double r = 1.0 / sqrt(var + 1e-5);
    const double alpha = (double)gg[d] * r;
    ab[aoff + d]       = (float)alpha;
    ab[aoff + 128 + d] = (float)((double)bee[d] - mean*alpha);
}

// ---------------------------------------------------------------------------
// Shared conv pieces (r13 proven).
__device__ __forceinline__ void load_afrag(
    bf16x8 (&afrag)[2][4], const float* __restrict__ Wf, int w, int lg, int lr)
{
    #pragma unroll
    for (int dtl = 0; dtl < 2; ++dtl)
        #pragma unroll
        for (int ks = 0; ks < 4; ++ks) {
            const float* wr = &Wf[(size_t)(32*w + 16*dtl + lr)*DIM + (4*ks + lg)*8];
            const float4 a4 = *(const float4*)wr;
            const float4 b4 = *(const float4*)(wr + 4);
            bf16x8 f;
            f[0]=(short)f2bs(a4.x); f[1]=(short)f2bs(a4.y); f[2]=(short)f2bs(a4.z); f[3]=(short)f2bs(a4.w);
            f[4]=(short)f2bs(b4.x); f[5]=(short)f2bs(b4.y); f[6]=(short)f2bs(b4.z); f[7]=(short)f2bs(b4.w);
            afrag[dtl][ks] = f;
        }
}

__device__ __forceinline__ void stage_h1(
    short* Hs, const float4* __restrict__ g4, const float* __restrict__ ab,
    int p0g, int w, int ln)
{
    const int sp = 64*(w & 1) + ln;
    const int ob = w >> 1;
    const float4 gq = g4[p0g + sp];
    #pragma unroll
    for (int it = 0; it < 8; ++it) {
        const int o = ob + 2*it;
        bf16x8 hv;
        #pragma unroll
        for (int j = 0; j < 8; ++j) {
            const int c = 8*o + j;
            const float4 wf = *(const float4*)&ab[AB_W1F + 4*c];
            const float h = fmaxf(__fmaf_rn(wf.x, gq.x, __fmaf_rn(wf.y, gq.y, __fmaf_rn(wf.z, gq.z, wf.w))), 0.f);
            hv[j] = (short)f2bs(h);
        }
        *(bf16x8*)&Hs[sp*128 + ((o ^ (sp & 7)) * 8)] = hv;
    }
}

#define MFMA_TILE(acc, afrag, Hs, lg, lr)                                             \
    _Pragma("unroll")                                                                 \
    for (int ks = 0; ks < 4; ++ks) {                                                  \
        _Pragma("unroll")                                                             \
        for (int pt = 0; pt < 8; ++pt) {                                              \
            const int p = 16*pt + lr;                                                 \
            const bf16x8 bf = *(const bf16x8*)&Hs[p*128 + (((4*ks + lg) ^ (lr & 7)) * 8)]; \
            acc[0][pt] = __builtin_amdgcn_mfma_f32_16x16x32_bf16(afrag[0][ks], bf, acc[0][pt], 0, 0, 0); \
            acc[1][pt] = __builtin_amdgcn_mfma_f32_16x16x32_bf16(afrag[1][ks], bf, acc[1][pt], 0, 0, 0); \
        }                                                                             \
    }

#define ZERO_ACC(acc)                                                                 \
    _Pragma("unroll")                                                                 \
    for (int i = 0; i < 2; ++i)                                                       \
        _Pragma("unroll")                                                             \
        for (int j = 0; j < 8; ++j) acc[i][j] = (f32x4){0.f,0.f,0.f,0.f};

// f64 BN finalize from banked stats -> affine; COHERENT (atomic) loads.
__device__ __forceinline__ void bn_affine(
    const double* __restrict__ stats, int soff, int d,
    const float* __restrict__ gg, const float* __restrict__ bee,
    float* a_out, float* e_out)
{
    double s1 = 0.0, s2 = 0.0;
    #pragma unroll
    for (int k = 0; k < NBANK; ++k) {
        s1 += aloadD(&stats[soff + k*256 + d]);
        s2 += aloadD(&stats[soff + k*256 + 128 + d]);
    }
    const double inv = 1.0 / (double)P_;
    const double mean = s1 * inv;
    double var = s2 * inv - mean*mean;
    if (var < 0.0) var = 0.0;
    const double r = 1.0 / sqrt(var + 1e-5);
    const double alpha = (double)gg[d] * r;
    *a_out = (float)alpha;
    *e_out = (float)((double)bee[d] - mean*alpha);
}

// ---------------------------------------------------------------------------
// Cooperative mega-kernel: conv2 (once) -> sync -> conv3 -> sync -> bn3max.
__global__ __launch_bounds__(256, 2) void mega_kernel(
    const float4* __restrict__ g4, const float* __restrict__ W2f,
    const float* __restrict__ W3f, const float* __restrict__ ab,
    const float* __restrict__ b2, const float* __restrict__ b3,
    const float* __restrict__ g2, const float* __restrict__ be2,
    const float* __restrict__ g3, const float* __restrict__ be3,
    float* __restrict__ ymm, double* __restrict__ stats,
    float* __restrict__ out)
{
    __shared__ __align__(16) short Hs[128*128];
    __shared__ float a2l[DIM], e2l[DIM], a3l[DIM], e3l[DIM];
    const int tid = threadIdx.x;
    const int bi  = blockIdx.x;
    const int w = tid >> 6, ln = tid & 63;
    const int lg = ln >> 4, lr = ln & 15;

    bf16x8 afrag[2][4];
    load_afrag(afrag, W2f, w, lg, lr);

    unsigned y2p[4][32];
    f32x4 acc[2][8];

    // ---------------- Phase A: conv2 + stats2, pack y2 ----------------
    #pragma unroll
    for (int t = 0; t < 4; ++t) {
        const int tile = 4*bi + t;
        const int p0g = tile * 128;
        if (t) __syncthreads();
        stage_h1(Hs, g4, ab, p0g, w, ln);
        __syncthreads();
        ZERO_ACC(acc);
        MFMA_TILE(acc, afrag, Hs, lg, lr);

        const int bank = tile & (NBANK-1);
        #pragma unroll
        for (int dtl = 0; dtl < 2; ++dtl) {
            const int d0 = 32*w + 16*dtl + 4*lg;
            const float4 bb4 = *(const float4*)&b2[d0];
            const float bbr[4] = {bb4.x, bb4.y, bb4.z, bb4.w};
            float vv[4][8];
            #pragma unroll
            for (int r = 0; r < 4; ++r)
                #pragma unroll
                for (int pt = 0; pt < 8; ++pt)
                    vv[r][pt] = acc[dtl][pt][r] + bbr[r];
            #pragma unroll
            for (int r = 0; r < 4; ++r) {
                const int d = d0 + r;
                float s1 = ((vv[r][0]+vv[r][1])+(vv[r][2]+vv[r][3]))
                         + ((vv[r][4]+vv[r][5])+(vv[r][6]+vv[r][7]));
                float s2 = ((vv[r][0]*vv[r][0]+vv[r][1]*vv[r][1])+(vv[r][2]*vv[r][2]+vv[r][3]*vv[r][3]))
                         + ((vv[r][4]*vv[r][4]+vv[r][5]*vv[r][5])+(vv[r][6]*vv[r][6]+vv[r][7]*vv[r][7]));
                s1 += dppf<DPP_XOR1>(s1);  s2 += dppf<DPP_XOR1>(s2);
                s1 += dppf<DPP_XOR2>(s1);  s2 += dppf<DPP_XOR2>(s2);
                s1 += dppf<DPP_HALFM>(s1); s2 += dppf<DPP_HALFM>(s2);
                s1 += dppf<DPP_MIRROR>(s1); s2 += dppf<DPP_MIRROR>(s2);
                if (lr == 0) {
                    atomAddD(&stats[I_S2 + bank*256 + d], (double)s1);
                    atomAddD(&stats[I_S2 + bank*256 + 128 + d], (double)s2);
                }
            }
            #pragma unroll
            for (int pt = 0; pt < 8; ++pt) {
                const unsigned u0 = (unsigned)f2bs(vv[0][pt]) | ((unsigned)f2bs(vv[1][pt]) << 16);
                const unsigned u1 = (unsigned)f2bs(vv[2][pt]) | ((unsigned)f2bs(vv[3][pt]) << 16);
                y2p[t][dtl*16 + pt*2]     = u0;
                y2p[t][dtl*16 + pt*2 + 1] = u1;
            }
        }
    }

    cg::this_grid().sync();

    // ---------------- a2/e2 per block (coherent stats reads) ----------
    if (tid < DIM) bn_affine(stats, I_S2, tid, g2, be2, &a2l[tid], &e2l[tid]);
    __syncthreads();

    load_afrag(afrag, W3f, w, lg, lr);

    // ---------------- Phase B: h2 -> conv3 + stats3 + minmax ----------
    #pragma unroll
    for (int t = 0; t < 4; ++t) {
        const int tile = 4*bi + t;
        __syncthreads();
        #pragma unroll
        for (int dtl = 0; dtl < 2; ++dtl) {
            const int d0 = 32*w + 16*dtl + 4*lg;
            const float aa[4] = {a2l[d0], a2l[d0+1], a2l[d0+2], a2l[d0+3]};
            const float ee[4] = {e2l[d0], e2l[d0+1], e2l[d0+2], e2l[d0+3]};
            const int oct = d0 >> 3, rem = d0 & 7;
            #pragma unroll
            for (int pt = 0; pt < 8; ++pt) {
                const unsigned u0 = y2p[t][dtl*16 + pt*2];
                const unsigned u1 = y2p[t][dtl*16 + pt*2 + 1];
                bf16x4 pk;
                pk[0] = (short)f2bs(fmaxf(__fmaf_rn(aa[0], bs2f((unsigned short)(u0 & 0xFFFF)), ee[0]), 0.f));
                pk[1] = (short)f2bs(fmaxf(__fmaf_rn(aa[1], bs2f((unsigned short)(u0 >> 16)),   ee[1]), 0.f));
                pk[2] = (short)f2bs(fmaxf(__fmaf_rn(aa[2], bs2f((unsigned short)(u1 & 0xFFFF)), ee[2]), 0.f));
                pk[3] = (short)f2bs(fmaxf(__fmaf_rn(aa[3], bs2f((unsigned short)(u1 >> 16)),   ee[3]), 0.f));
                const int p = 16*pt + lr;
                *(bf16x4*)&Hs[p*128 + ((oct ^ (p & 7)) * 8 + rem)] = pk;
            }
        }
        __syncthreads();
        ZERO_ACC(acc);
        MFMA_TILE(acc, afrag, Hs, lg, lr);

        const int bank = tile & (NBANK-1);
        #pragma unroll
        for (int dtl = 0; dtl < 2; ++dtl) {
            #pragma unroll
            for (int r = 0; r < 4; ++r) {
                const int d = 32*w + 16*dtl + 4*lg + r;
                const float bb = b3[d];
                float v[8];
                #pragma unroll
                for (int pt = 0; pt < 8; ++pt) v[pt] = acc[dtl][pt][r] + bb;

                float s1 = ((v[0]+v[1])+(v[2]+v[3])) + ((v[4]+v[5])+(v[6]+v[7]));
                float s2 = ((v[0]*v[0]+v[1]*v[1])+(v[2]*v[2]+v[3]*v[3]))
                         + ((v[4]*v[4]+v[5]*v[5])+(v[6]*v[6]+v[7]*v[7]));
                s1 += dppf<DPP_XOR1>(s1);  s2 += dppf<DPP_XOR1>(s2);
                s1 += dppf<DPP_XOR2>(s1);  s2 += dppf<DPP_XOR2>(s2);
                s1 += dppf<DPP_HALFM>(s1); s2 += dppf<DPP_HALFM>(s2);
                s1 += dppf<DPP_MIRROR>(s1); s2 += dppf<DPP_MIRROR>(s2);
                if (lr == 0) {
                    atomAddD(&stats[I_S3 + bank*256 + d], (double)s1);
                    atomAddD(&stats[I_S3 + bank*256 + 128 + d], (double)s2);
                }

                #pragma unroll
                for (int pt = 0; pt < 8; ++pt) {
                    float mx = v[pt], mn = v[pt];
                    mx = fmaxf(mx, dppf<DPP_XOR1>(mx));  mn = fminf(mn, dppf<DPP_XOR1>(mn));
                    mx = fmaxf(mx, dppf<DPP_XOR2>(mx));  mn = fminf(mn, dppf<DPP_XOR2>(mn));
                    mx = fmaxf(mx, dppf<DPP_HALFM>(mx)); mn = fminf(mn, dppf<DPP_HALFM>(mn));
                    if ((lr & 7) == 0) {
                        const int slot = 2*pt + (lr >> 3);
                        float* yb = ymm + ((size_t)d*NBLK + tile)*32;
                        yb[slot]      = mx;
                        yb[16 + slot] = mn;
                    }
                }
            }
        }
    }

    cg::this_grid().sync();

    // ---------------- a3/e3 + Phase C: bn3max (own 64 points) ---------
    if (tid < DIM) bn_affine(stats, I_S3, tid, g3, be3, &a3l[tid], &e3l[tid]);
    __syncthreads();

    const int bO = bi >> 5;
    const int n0 = (bi << 6) & (N_-1);
    const int n  = n0 + ln;
    const int tileC = 4*bi + (ln >> 4);
    const int pit = ln & 15;
    #pragma unroll 4
    for (int dd = 0; dd < 32; ++dd) {
        const int d = 32*w + dd;
        const float a = a3l[d], e = e3l[d];
        const size_t yb = ((size_t)d*NBLK + tileC)*32 + pit;
        const float mx = ymm[yb];
        const float mn = ymm[yb + 16];
        const float vv = (a >= 0.f) ? mx : mn;
        out[((size_t)(bO*DIM + d))*N_ + n] = fmaxf(__fmaf_rn(a, vv, e), 0.f);
    }
}

// ---------------------------------------------------------------------------
// Fallback pipeline (r13 proven): conv2stats -> convfused -> bn3max.
__global__ __launch_bounds__(256) void conv2stats_kernel(
    const float4* __restrict__ g4, const float* __restrict__ Wf,
    const float* __restrict__ ab, const float* __restrict__ bias,
    double* __restrict__ stats)
{
    __shared__ __align__(16) short Hs[128*128];
    const int tid = threadIdx.x;
    const int p0g = blockIdx.x * 128;
    const int w  = tid >> 6, ln = tid & 63;
    const int lg = ln >> 4, lr = ln & 15;

    bf16x8 afrag[2][4];
    load_afrag(afrag, Wf, w, lg, lr);
    stage_h1(Hs, g4, ab, p0g, w, ln);
    __syncthreads();

    f32x4 acc[2][8];
    ZERO_ACC(acc);
    MFMA_TILE(acc, afrag, Hs, lg, lr);

    const int bank = blockIdx.x & (NBANK-1);
    #pragma unroll
    for (int dtl = 0; dtl < 2; ++dtl) {
        #pragma unroll
        for (int r = 0; r < 4; ++r) {
            const int d = 32*w + 16*dtl + 4*lg + r;
            const float bb = bias[d];
            float v[8];
            #pragma unroll
            for (int pt = 0; pt < 8; ++pt) v[pt] = acc[dtl][pt][r] + bb;
            float s1 = ((v[0]+v[1])+(v[2]+v[3])) + ((v[4]+v[5])+(v[6]+v[7]));
            float s2 = ((v[0]*v[0]+v[1]*v[1])+(v[2]*v[2]+v[3]*v[3]))
                     + ((v[4]*v[4]+v[5]*v[5])+(v[6]*v[6]+v[7]*v[7]));
            s1 += dppf<DPP_XOR1>(s1);  s2 += dppf<DPP_XOR1>(s2);
            s1 += dppf<DPP_XOR2>(s1);  s2 += dppf<DPP_XOR2>(s2);
            s1 += dppf<DPP_HALFM>(s1); s2 += dppf<DPP_HALFM>(s2);
            s1 += dppf<DPP_MIRROR>(s1); s2 += dppf<DPP_MIRROR>(s2);
            if (lr == 0) {
                atomAddD(&stats[I_S2 + bank*256 + d], (double)s1);
                atomAddD(&stats[I_S2 + bank*256 + 128 + d], (double)s2);
            }
        }
    }
}

__global__ __launch_bounds__(256) void convfused_kernel(
    const float4* __restrict__ g4, const float* __restrict__ W2f,
    const float* __restrict__ W3f, const float* __restrict__ ab,
    const float* __restrict__ b2, const float* __restrict__ b3,
    float* __restrict__ ymm, double* __restrict__ stats)
{
    __shared__ __align__(16) short Hs[128*128];
    const int tid = threadIdx.x;
    const int p0g = blockIdx.x * 128;
    const int w  = tid >> 6, ln = tid & 63;
    const int lg = ln >> 4, lr = ln & 15;

    bf16x8 afrag[2][4];
    load_afrag(afrag, W2f, w, lg, lr);
    stage_h1(Hs, g4, ab, p0g, w, ln);
    __syncthreads();

    f32x4 acc[2][8];
    ZERO_ACC(acc);
    MFMA_TILE(acc, afrag, Hs, lg, lr);

    __syncthreads();

    #pragma unroll
    for (int dtl = 0; dtl < 2; ++dtl) {
        const int d0 = 32*w + 16*dtl + 4*lg;
        const float4 bb = *(const float4*)&b2[d0];
        const float4 a2v = *(const float4*)&ab[AB_A2 + d0];
        const float4 e2v = *(const float4*)&ab[AB_E2 + d0];
        const float bbv[4] = {bb.x, bb.y, bb.z, bb.w};
        const float aav[4] = {a2v.x, a2v.y, a2v.z, a2v.w};
        const float eev[4] = {e2v.x, e2v.y, e2v.z, e2v.w};
        const int oct = d0 >> 3, rem = d0 & 7;
        #pragma unroll
        for (int pt = 0; pt < 8; ++pt) {
            const int p = 16*pt + lr;
            bf16x4 pk;
            #pragma unroll
            for (int j = 0; j < 4; ++j) {
                const float y = acc[dtl][pt][j] + bbv[j];
                pk[j] = (short)f2bs(fmaxf(__fmaf_rn(aav[j], y, eev[j]), 0.f));
            }
            *(bf16x4*)&Hs[p*128 + ((oct ^ (p & 7)) * 8 + rem)] = pk;
        }
    }

    load_afrag(afrag, W3f, w, lg, lr);
    ZERO_ACC(acc);
    __syncthreads();

    MFMA_TILE(acc, afrag, Hs, lg, lr);

    const int bank = blockIdx.x & (NBANK-1);
    #pragma unroll
    for (int dtl = 0; dtl < 2; ++dtl) {
        #pragma unroll
        for (int r = 0; r < 4; ++r) {
            const int d = 32*w + 16*dtl + 4*lg + r;
            const float bb = b3[d];
            float v[8];
            #pragma unroll
            for (int pt = 0; pt < 8; ++pt) v[pt] = acc[dtl][pt][r] + bb;

            float s1 = ((v[0]+v[1])+(v[2]+v[3])) + ((v[4]+v[5])+(v[6]+v[7]));
            float s2 = ((v[0]*v[0]+v[1]*v[1])+(v[2]*v[2]+v[3]*v[3]))
                     + ((v[4]*v[4]+v[5]*v[5])+(v[6]*v[6]+v[7]*v[7]));
            s1 += dppf<DPP_XOR1>(s1);  s2 += dppf<DPP_XOR1>(s2);
            s1 += dppf<DPP_XOR2>(s1);  s2 += dppf<DPP_XOR2>(s2);
            s1 += dppf<DPP_HALFM>(s1); s2 += dppf<DPP_HALFM>(s2);
            s1 += dppf<DPP_MIRROR>(s1); s2 += dppf<DPP_MIRROR>(s2);
            if (lr == 0) {
                atomAddD(&stats[I_S3 + bank*256 + d], (double)s1);
                atomAddD(&stats[I_S3 + bank*256 + 128 + d], (double)s2);
            }

            #pragma unroll
            for (int pt = 0; pt < 8; ++pt) {
                float mx = v[pt], mn = v[pt];
                mx = fmaxf(mx, dppf<DPP_XOR1>(mx));  mn = fminf(mn, dppf<DPP_XOR1>(mn));
                mx = fmaxf(mx, dppf<DPP_XOR2>(mx));  mn = fminf(mn, dppf<DPP_XOR2>(mn));
                mx = fmaxf(mx, dppf<DPP_HALFM>(mx)); mn = fminf(mn, dppf<DPP_HALFM>(mn));
                if ((lr & 7) == 0) {
                    const int slot = 2*pt + (lr >> 3);
                    float* yb = ymm + ((size_t)d*NBLK + blockIdx.x)*32;
                    yb[slot]      = mx;
                    yb[16 + slot] = mn;
                }
            }
        }
    }
}

__global__ __launch_bounds__(256) void bn3max_kernel(
    const float* __restrict__ ymm, const float* __restrict__ ab, float* __restrict__ out)
{
    const int idx = blockIdx.x*256 + threadIdx.x;
    const int n = idx & (N_-1);
    const int d = (idx >> 11) & (DIM-1);
    const int b = idx >> 18;
    const int pt  = b*N_ + n;
    const int blk = pt >> 4;
    const int j   = pt & 15;
    const size_t base = ((size_t)d*NBLK + blk) * 32;
    const float a = ab[AB_A3 + d], e = ab[AB_E3 + d];
    const float mx = ymm[base + j];
    const float mn = ymm[base + 16 + j];
    const float v = (a >= 0.f) ? mx : mn;
    out[idx] = fmaxf(__fmaf_rn(a, v, e), 0.f);
}

// ---------------------------------------------------------------------------
extern "C" void kernel_launch(void* const* d_in, const int* in_sizes, int n_in,
                              void* d_out, int out_size, void* d_ws, size_t ws_size,
                              hipStream_t stream) {
    (void)in_sizes; (void)n_in; (void)out_size; (void)ws_size;
    const float* x   = (const float*)d_in[0];
    const float* W1  = (const float*)d_in[1];
    const float* b1  = (const float*)d_in[2];
    const float* g1  = (const float*)d_in[3];
    const float* be1 = (const float*)d_in[4];
    const float* W2  = (const float*)d_in[5];
    const float* b2  = (const float*)d_in[6];
    const float* g2  = (const float*)d_in[7];
    const float* be2 = (const float*)d_in[8];
    const float* W3  = (const float*)d_in[9];
    const float* b3  = (const float*)d_in[10];
    const float* g3  = (const float*)d_in[11];
    const float* be3 = (const float*)d_in[12];

    float*  out = (float*)d_out;
    char*   ws  = (char*)d_ws;
    float4*         g4  = (float4*)(ws + OFF_G);
    double*         st  = (double*)(ws + OFF_STATS);
    float*          ab  = (float*)(ws + OFF_AB);
    float*          kp  = (float*)(ws + OFF_KPART);
    float*          ymm = (float*)(ws + OFF_YMM);

    knn_group_kernel<<<dim3(128, B_), 1024, 0, stream>>>(x, g4, kp, st);
    finalize1_kernel<<<1, 1024, 0, stream>>>(kp, W1, b1, g1, be1, ab);

    void* args[] = {
        (void*)&g4, (void*)&W2, (void*)&W3, (void*)&ab,
        (void*)&b2, (void*)&b3, (void*)&g2, (void*)&be2,
        (void*)&g3, (void*)&be3, (void*)&ymm, (void*)&st, (void*)&out
    };
    hipError_t err = hipLaunchCooperativeKernel((void*)mega_kernel, dim3(MGRID),
                                                dim3(256), args, 0, stream);
    if (err != hipSuccess) {
        // Fallback: r13-proven non-cooperative pipeline.
        conv2stats_kernel<<<NBLK, 256, 0, stream>>>(g4, W2, ab, b2, st);
        finalize23_kernel<<<1, 128, 0, stream>>>(st, I_S2, g2, be2, ab, AB_A2);
        convfused_kernel<<<NBLK, 256, 0, stream>>>(g4, W2, W3, ab, b2, b3, ymm, st);
        finalize23_kernel<<<1, 128, 0, stream>>>(st, I_S3, g3, be3, ab, AB_A3);
        bn3max_kernel<<<(B_*DIM*N_)/256, 256, 0, stream>>>(ymm, ab, out);
    }
}

// Round 16
// 194.537 us; speedup vs baseline: 1.9828x; 1.9828x over previous
//
#include <hip/hip_runtime.h>
#include <hip/hip_bf16.h>
#include <math.h>

// ---------------------------------------------------------------------------
// FeatureNet (DGCNN edge-conv block), MI355X / gfx950, round 16.
//
// Round-16 = round-11 proven pipeline (193.7us) + ONE delta:
//  * ymm packed: (max,min) per (d,point) as 2xbf16 in one u32
//    (33.5 -> 16.8 MB; conv3 minmax stores and bn3max loads halved).
// Fusion experiments r12-r15 all lost to this structure; reverted.
// ---------------------------------------------------------------------------

#define B_   16
#define N_   2048
#define KNN  8
#define DIM  128
#define P_   (B_*N_*KNN)   // 262144
#define CAP  128
#define NBLK 2048          // conv blocks (128 p each)

typedef __attribute__((ext_vector_type(8))) short bf16x8;
typedef __attribute__((ext_vector_type(4))) short bf16x4;
typedef __attribute__((ext_vector_type(4))) float f32x4;

// ws layout (bytes)
#define OFF_G     0ull
#define SZ_G      ((size_t)3*P_*4)             // g planes (r11 layout)
#define OFF_Y2B   (OFF_G + SZ_G)
#define SZ_Y2B    ((size_t)DIM*P_*2)           // 67,108,864  (y2t[p][c])
#define OFF_STATS (OFF_Y2B + SZ_Y2B)
#define N_STATS   4112
#define SZ_STATS  ((size_t)N_STATS*8)
#define OFF_AB    (OFF_STATS + SZ_STATS)
#define SZ_AB     4096ull
#define OFF_KPART (OFF_AB + SZ_AB)
#define NKBLK     2048
#define SZ_KPART  ((size_t)9*NKBLK*4)
#define OFF_YMM   (OFF_KPART + SZ_KPART)
#define SZ_YMM    ((size_t)DIM*NBLK*16*4)      // 16,777,216 (packed u32)

// stats (f64) indices
#define I_S2   16
#define I_S3   (16 + 8*256)
#define NBANK  8

// ab (float) layout
#define AB_W1F 0
#define AB_A2  512
#define AB_E2  640
#define AB_A3  768
#define AB_E3  896

// DPP ctrl codes (all source lanes valid)
#define DPP_XOR1   0xB1    // quad_perm [1,0,3,2]
#define DPP_XOR2   0x4E    // quad_perm [2,3,0,1]
#define DPP_HALFM  0x141   // row_half_mirror: lane ^ 7
#define DPP_MIRROR 0x140   // row_mirror: lane ^ 15

template<int C>
__device__ __forceinline__ float dppf(float v) {
    return __int_as_float(__builtin_amdgcn_update_dpp(
        __float_as_int(v), __float_as_int(v), C, 0xF, 0xF, false));
}

__device__ __forceinline__ void atomAddD(double* p, double v) {
    __hip_atomic_fetch_add(p, v, __ATOMIC_RELAXED, __HIP_MEMORY_SCOPE_AGENT);
}
__device__ __forceinline__ unsigned short f2bs(float f) {
    const unsigned b = __float_as_uint(f);
    return (unsigned short)((b + 0x7FFFu + ((b >> 16) & 1u)) >> 16);   // RNE
}
__device__ __forceinline__ float bs2f(unsigned short u) {
    return __uint_as_float(((unsigned)u) << 16);
}

// ---------------------------------------------------------------------------
// kNN + grouped offsets + layer-1 moment partials + stats zeroing (block 0,0).
// (r11 proven: bitonic Pass C, b64 keys, float4 Pass A, cheap bound)
__global__ __launch_bounds__(1024) void knn_group_kernel(
    const float* __restrict__ x, float* __restrict__ g,
    float* __restrict__ kpart, double* __restrict__ st)
{
    __shared__ __align__(16) float4 xs4[N_];           // 32 KB {x,y,z,|x|^2}
    __shared__ unsigned long long listK[16][CAP];      // 16 KB packed keys
    __shared__ float spart[16][12];
    const int b   = blockIdx.y;
    const int tid = threadIdx.x;
    const int wv  = tid >> 6;
    const int ln  = tid & 63;
    const int n   = blockIdx.x * 16 + wv;
    const float* xb = x + (size_t)b * 3 * N_;

    if (blockIdx.x == 0 && blockIdx.y == 0)
        for (int i = tid; i < N_STATS; i += 1024) st[i] = 0.0;

    for (int i = tid; i < N_; i += 1024) {
        const float a0 = xb[i], a1 = xb[N_ + i], a2 = xb[2*N_ + i];
        const float sq = __fadd_rn(__fadd_rn(__fmul_rn(a0,a0), __fmul_rn(a1,a1)), __fmul_rn(a2,a2));
        xs4[i] = make_float4(a0, a1, a2, sq);
    }
    __syncthreads();

    const float4 me = xs4[n];
    const float xn0 = me.x, xn1 = me.y, xn2 = me.z, sqn = me.w;

    // ---- Pass A: distances in registers + lane min
    float dreg[32];
    float lmin = INFINITY;
    #pragma unroll
    for (int i = 0; i < 32; ++i) {
        const float4 q = xs4[ln + 64*i];
        dreg[i] = __fadd_rn(__fmaf_rn(-2.f, __fmaf_rn(xn2, q.z, __fmaf_rn(xn1, q.y, __fmul_rn(xn0, q.x))), sqn), q.w);
        lmin = fminf(lmin, dreg[i]);
    }

    // ---- bound B' = max over 8 groups of (min over each 8-lane group)
    float gm = lmin;
    gm = fminf(gm, __shfl_xor(gm, 1));
    gm = fminf(gm, __shfl_xor(gm, 2));
    gm = fminf(gm, __shfl_xor(gm, 4));
    float Bb = gm;
    Bb = fmaxf(Bb, __shfl_xor(Bb, 8));
    Bb = fmaxf(Bb, __shfl_xor(Bb, 16));
    Bb = fmaxf(Bb, __shfl_xor(Bb, 32));

    // ---- Pass B: ballot-compact packed keys (orderable(d)<<32 | idx)
    unsigned base = 0;
    #pragma unroll
    for (int i = 0; i < 32; ++i) {
        const bool pred = (dreg[i] <= Bb);
        const unsigned long long mk = __ballot(pred);
        if (pred) {
            const unsigned pos = base + (unsigned)__popcll(mk & ((1ull << ln) - 1ull));
            if (pos < CAP) {
                const unsigned u = __float_as_uint(dreg[i]);
                const unsigned od = u ^ ((unsigned)(((int)u) >> 31) | 0x80000000u);
                listK[wv][pos] = (((unsigned long long)od) << 32) | (unsigned)(ln + 64*i);
            }
        }
        base += (unsigned)__popcll(mk);
    }
    const int cnt = (base < CAP) ? (int)base : CAP;

    // ---- Pass C: exact top-8 selection (lex (d,idx) == lax.top_k order)
    int myi = 0;
    if (cnt <= 64) {
        unsigned long long K = (ln < cnt) ? listK[wv][ln] : ~0ull;
        #pragma unroll
        for (int k = 2; k <= 64; k <<= 1) {
            #pragma unroll
            for (int j = k >> 1; j >= 1; j >>= 1) {
                const unsigned long long o = __shfl_xor(K, j);
                const bool takeMin = (((ln & j) == 0) == ((ln & k) == 0));
                const bool oLess = (o < K);
                if (takeMin ? oLess : !oLess) K = o;
            }
        }
        myi = (int)(unsigned)K;
    } else {
        unsigned long long K0 = (ln < cnt)      ? listK[wv][ln]      : ~0ull;
        unsigned long long K1 = (ln + 64 < cnt) ? listK[wv][ln + 64] : ~0ull;
        #pragma unroll
        for (int sel = 0; sel < 8; ++sel) {
            unsigned long long p = (K1 < K0) ? K1 : K0;
            #pragma unroll
            for (int m = 1; m < 64; m <<= 1) {
                const unsigned long long o = __shfl_xor(p, m);
                if (o < p) p = o;
            }
            if (ln == sel) myi = (int)(unsigned)p;
            if (K0 == p) K0 = ~0ull;
            if (K1 == p) K1 = ~0ull;
        }
    }

    // ---- gather, g-write, stats (lanes 0..7 hold the 8 neighbors)
    if (ln < 8) {
        const float4 q = xs4[myi];
        const float g0  = q.x - xn0;
        const float g1v = q.y - xn1;
        const float g2v = q.z - xn2;
        const size_t basep = ((size_t)b*N_ + n) * KNN;
        g[0*P_ + basep + ln] = g0;
        g[1*P_ + basep + ln] = g1v;
        g[2*P_ + basep + ln] = g2v;
        float s0 = g0, s1 = g1v, s2 = g2v;
        float s00 = g0*g0, s01 = g0*g1v, s02 = g0*g2v;
        float s11 = g1v*g1v, s12 = g1v*g2v, s22 = g2v*g2v;
        #pragma unroll
        for (int m = 1; m < 8; m <<= 1) {
            s0 += __shfl_xor(s0, m);  s1 += __shfl_xor(s1, m);  s2 += __shfl_xor(s2, m);
            s00 += __shfl_xor(s00, m); s01 += __shfl_xor(s01, m); s02 += __shfl_xor(s02, m);
            s11 += __shfl_xor(s11, m); s12 += __shfl_xor(s12, m); s22 += __shfl_xor(s22, m);
        }
        if (ln == 0) {
            spart[wv][0] = s0;  spart[wv][1] = s1;  spart[wv][2] = s2;
            spart[wv][3] = s00; spart[wv][4] = s01; spart[wv][5] = s02;
            spart[wv][6] = s11; spart[wv][7] = s12; spart[wv][8] = s22;
        }
    }
    __syncthreads();
    if (tid < 9) {
        float a = 0.f;
        #pragma unroll
        for (int w = 0; w < 16; ++w) a += spart[w][tid];
        kpart[tid*NKBLK + blockIdx.y*128 + blockIdx.x] = a;
    }
}

// ---------------------------------------------------------------------------
// Layer-1 BN stats from g moment partials (wave-parallel reduce); emit W1f.
__global__ __launch_bounds__(1024) void finalize1_kernel(
    const float* __restrict__ kpart, const float* __restrict__ W1,
    const float* __restrict__ b1, const float* __restrict__ g1,
    const float* __restrict__ be1, float* __restrict__ ab)
{
    __shared__ double S9[9];
    const int tid = threadIdx.x;
    const int w = tid >> 6, l = tid & 63;
    if (w < 9) {
        double a = 0.0;
        #pragma unroll
        for (int i = 0; i < 32; ++i) a += (double)kpart[w*NKBLK + l + 64*i];
        #pragma unroll
        for (int m = 1; m < 64; m <<= 1) a += __shfl_xor(a, m);
        if (l == 0) S9[w] = a;
    }
    __syncthreads();
    if (tid < 128) {
        const int d = tid;
        const double inv = 1.0 / (double)P_;
        const double mu0 = S9[0]*inv, mu1 = S9[1]*inv, mu2 = S9[2]*inv;
        const double c00 = S9[3]*inv - mu0*mu0;
        const double c01 = S9[4]*inv - mu0*mu1;
        const double c02 = S9[5]*inv - mu0*mu2;
        const double c11 = S9[6]*inv - mu1*mu1;
        const double c12 = S9[7]*inv - mu1*mu2;
        const double c22 = S9[8]*inv - mu2*mu2;
        const double w0 = W1[d*3+0], w1 = W1[d*3+1], w2 = W1[d*3+2];
        const double mean = w0*mu0 + w1*mu1 + w2*mu2 + (double)b1[d];
        double var = w0*w0*c00 + w1*w1*c11 + w2*w2*c22
                   + 2.0*(w0*w1*c01 + w0*w2*c02 + w1*w2*c12);
        if (var < 0.0) var = 0.0;
        const double r = 1.0 / sqrt(var + 1e-5);
        const double alpha = (double)g1[d] * r;
        const double beta  = (double)be1[d] - mean*alpha;
        ab[AB_W1F + 4*d + 0] = (float)(alpha * w0);
        ab[AB_W1F + 4*d + 1] = (float)(alpha * w1);
        ab[AB_W1F + 4*d + 2] = (float)(alpha * w2);
        ab[AB_W1F + 4*d + 3] = (float)(alpha * (double)b1[d] + beta);
    }
}

__global__ void finalize23_kernel(
    const double* __restrict__ st, int soff,
    const float* __restrict__ gg, const float* __restrict__ bee,
    float* __restrict__ ab, int aoff)
{
    const int d = threadIdx.x;
    if (d >= DIM) return;
    double s1 = 0.0, s2 = 0.0;
    #pragma unroll
    for (int k = 0; k < NBANK; ++k) {
        s1 += st[soff + k*256 + d];
        s2 += st[soff + k*256 + 128 + d];
    }
    const double inv = 1.0 / (double)P_;
    const double mean = s1 * inv;
    double var = s2 * inv - mean*mean;
    if (var < 0.0) var = 0.0;
    const double r = 1.0 / sqrt(var + 1e-5);
    const double alpha = (double)gg[d] * r;
    ab[aoff + d]       = (float)alpha;
    ab[aoff + 128 + d] = (float)((double)bee[d] - mean*alpha);
}

// ---------------------------------------------------------------------------
// MFMA conv (r11 proven): block = 128d x 128p, 4 waves; wave w owns
// d in [32w,32w+32). Ht[p][c] bf16 in LDS (c-octet XOR(p&7) swizzle).
// A-frags loaded from f32 W[d][c] + in-reg bf16 cast.
// Stats/minmax reductions via DPP.
// SRC 0: H from g via folded W1f (conv2).
// SRC 1: H = relu(a2*y2t+e2), y2t p-major, coalesced b128 row loads (conv3).
// MODE 0: y2t (bf16, p-major) via LDS transpose (stride 136) + stats.
// MODE 3: stats + per-point max/min packed bf16x2 -> ymm (u32).
template<int SRC, int MODE>
__global__ __launch_bounds__(256) void conv_kernel(
    const float* __restrict__ gsrc, const unsigned short* __restrict__ ybsrc,
    const float* __restrict__ Wf, const float* __restrict__ ab,
    const float* __restrict__ bias, unsigned short* __restrict__ ybdst,
    unsigned* __restrict__ ymm, double* __restrict__ stats, int statoff)
{
    __shared__ __align__(16) short Hs[128*136];   // staging stride 128; transpose stride 136
    const int tid = threadIdx.x;
    const int p0g = blockIdx.x * 128;
    const int w  = tid >> 6, ln = tid & 63;
    const int lg = ln >> 4, lr = ln & 15;

    bf16x8 afrag[2][4];
    #pragma unroll
    for (int dtl = 0; dtl < 2; ++dtl)
        #pragma unroll
        for (int ks = 0; ks < 4; ++ks) {
            const float* wr = &Wf[(size_t)(32*w + 16*dtl + lr)*DIM + (4*ks + lg)*8];
            const float4 a4 = *(const float4*)wr;
            const float4 b4 = *(const float4*)(wr + 4);
            bf16x8 f;
            f[0]=(short)f2bs(a4.x); f[1]=(short)f2bs(a4.y); f[2]=(short)f2bs(a4.z); f[3]=(short)f2bs(a4.w);
            f[4]=(short)f2bs(b4.x); f[5]=(short)f2bs(b4.y); f[6]=(short)f2bs(b4.z); f[7]=(short)f2bs(b4.w);
            afrag[dtl][ks] = f;
        }

    if constexpr (SRC == 0) {
        const int sp = 64*(w & 1) + ln;     // 0..127
        const int ob = w >> 1;              // 0 or 1
        const float gx = gsrc[0*P_ + p0g + sp];
        const float gy = gsrc[1*P_ + p0g + sp];
        const float gz = gsrc[2*P_ + p0g + sp];
        #pragma unroll
        for (int it = 0; it < 8; ++it) {
            const int o = ob + 2*it;
            bf16x8 hv;
            #pragma unroll
            for (int j = 0; j < 8; ++j) {
                const int c = 8*o + j;
                const float4 wf = *(const float4*)&ab[AB_W1F + 4*c];
                const float h = fmaxf(__fmaf_rn(wf.x, gx, __fmaf_rn(wf.y, gy, __fmaf_rn(wf.z, gz, wf.w))), 0.f);
                hv[j] = (short)f2bs(h);
            }
            *(bf16x8*)&Hs[sp*128 + ((o ^ (sp & 7)) * 8)] = hv;
        }
    } else {
        const int myoct = tid & 15;          // fixed c-octet per thread
        const float4 aLo = *(const float4*)&ab[AB_A2 + myoct*8];
        const float4 aHi = *(const float4*)&ab[AB_A2 + myoct*8 + 4];
        const float4 eLo = *(const float4*)&ab[AB_E2 + myoct*8];
        const float4 eHi = *(const float4*)&ab[AB_E2 + myoct*8 + 4];
        const float av[8] = {aLo.x,aLo.y,aLo.z,aLo.w,aHi.x,aHi.y,aHi.z,aHi.w};
        const float ev[8] = {eLo.x,eLo.y,eLo.z,eLo.w,eHi.x,eHi.y,eHi.z,eHi.w};
        #pragma unroll
        for (int it = 0; it < 8; ++it) {
            const int p = it*16 + (tid >> 4);
            const bf16x8 raw = *(const bf16x8*)&ybsrc[(size_t)(p0g + p)*128 + myoct*8];
            bf16x8 hv;
            #pragma unroll
            for (int j = 0; j < 8; ++j) {
                const float v = bs2f((unsigned short)raw[j]);
                hv[j] = (short)f2bs(fmaxf(__fmaf_rn(av[j], v, ev[j]), 0.f));
            }
            *(bf16x8*)&Hs[p*128 + ((myoct ^ (p & 7)) * 8)] = hv;
        }
    }
    __syncthreads();

    f32x4 acc[2][8];
    #pragma unroll
    for (int i = 0; i < 2; ++i)
        #pragma unroll
        for (int j = 0; j < 8; ++j)
            acc[i][j] = (f32x4){0.f, 0.f, 0.f, 0.f};

    #pragma unroll
    for (int ks = 0; ks < 4; ++ks) {
        #pragma unroll
        for (int pt = 0; pt < 8; ++pt) {
            const int p = 16*pt + lr;
            const bf16x8 bf = *(const bf16x8*)&Hs[p*128 + (((4*ks + lg) ^ (lr & 7)) * 8)];
            acc[0][pt] = __builtin_amdgcn_mfma_f32_16x16x32_bf16(afrag[0][ks], bf, acc[0][pt], 0, 0, 0);
            acc[1][pt] = __builtin_amdgcn_mfma_f32_16x16x32_bf16(afrag[1][ks], bf, acc[1][pt], 0, 0, 0);
        }
    }

    // ---- stats (both modes) + MODE 3 packed minmax, reductions on DPP
    const int bank = blockIdx.x & (NBANK-1);
    #pragma unroll
    for (int dtl = 0; dtl < 2; ++dtl) {
        #pragma unroll
        for (int r = 0; r < 4; ++r) {
            const int d = 32*w + 16*dtl + 4*lg + r;
            const float bb = bias[d];
            float v[8];
            #pragma unroll
            for (int pt = 0; pt < 8; ++pt) v[pt] = acc[dtl][pt][r] + bb;

            float s1 = ((v[0]+v[1])+(v[2]+v[3])) + ((v[4]+v[5])+(v[6]+v[7]));
            float s2 = ((v[0]*v[0]+v[1]*v[1])+(v[2]*v[2]+v[3]*v[3]))
                     + ((v[4]*v[4]+v[5]*v[5])+(v[6]*v[6]+v[7]*v[7]));
            s1 += dppf<DPP_XOR1>(s1);  s2 += dppf<DPP_XOR1>(s2);
            s1 += dppf<DPP_XOR2>(s1);  s2 += dppf<DPP_XOR2>(s2);
            s1 += dppf<DPP_HALFM>(s1); s2 += dppf<DPP_HALFM>(s2);
            s1 += dppf<DPP_MIRROR>(s1); s2 += dppf<DPP_MIRROR>(s2);
            if (lr == 0) {
                atomAddD(&stats[statoff + bank*256 + d], (double)s1);
                atomAddD(&stats[statoff + bank*256 + 128 + d], (double)s2);
            }

            if constexpr (MODE == 3) {
                #pragma unroll
                for (int pt = 0; pt < 8; ++pt) {
                    float mx = v[pt], mn = v[pt];
                    mx = fmaxf(mx, dppf<DPP_XOR1>(mx));  mn = fminf(mn, dppf<DPP_XOR1>(mn));
                    mx = fmaxf(mx, dppf<DPP_XOR2>(mx));  mn = fminf(mn, dppf<DPP_XOR2>(mn));
                    mx = fmaxf(mx, dppf<DPP_HALFM>(mx)); mn = fminf(mn, dppf<DPP_HALFM>(mn));
                    if ((lr & 7) == 0) {
                        const int slot = 2*pt + (lr >> 3);
                        // packed: low16 = max (bf16), high16 = min (bf16)
                        ymm[((size_t)d*NBLK + blockIdx.x)*16 + slot] =
                            (unsigned)f2bs(mx) | ((unsigned)f2bs(mn) << 16);
                    }
                }
            }
        }
    }

    if constexpr (MODE == 0) {
        // ---- LDS transpose -> fully coalesced p-major stores
        __syncthreads();   // all waves done reading Hs (B-frags)
        #pragma unroll
        for (int dtl = 0; dtl < 2; ++dtl) {
            const int d0 = 32*w + 16*dtl + 4*lg;
            const float4 b4 = *(const float4*)&bias[d0];
            #pragma unroll
            for (int pt = 0; pt < 8; ++pt) {
                const int p = 16*pt + lr;
                bf16x4 pk;
                pk[0] = (short)f2bs(acc[dtl][pt][0] + b4.x);
                pk[1] = (short)f2bs(acc[dtl][pt][1] + b4.y);
                pk[2] = (short)f2bs(acc[dtl][pt][2] + b4.z);
                pk[3] = (short)f2bs(acc[dtl][pt][3] + b4.w);
                *(bf16x4*)&Hs[p*136 + d0] = pk;
            }
        }
        __syncthreads();
        #pragma unroll
        for (int it = 0; it < 8; ++it) {
            const int f = it*256 + tid;
            const int row = f >> 4, ch = f & 15;
            const bf16x8 vv = *(const bf16x8*)&Hs[row*136 + ch*8];
            *(bf16x8*)&ybdst[(size_t)(p0g + row)*128 + ch*8] = vv;
        }
    }
}

// ---------------------------------------------------------------------------
// Epilogue: out[b,d,n] = relu(a3*(a3>=0 ? max_k : min_k) + e3), packed ymm.
__global__ __launch_bounds__(256) void bn3max_kernel(
    const unsigned* __restrict__ ymm, const float* __restrict__ ab, float* __restrict__ out)
{
    const int idx = blockIdx.x*256 + threadIdx.x;   // over B*DIM*N
    const int n = idx & (N_-1);
    const int d = (idx >> 11) & (DIM-1);
    const int b = idx >> 18;
    const int pt  = b*N_ + n;
    const int blk = pt >> 4;
    const int j   = pt & 15;
    const unsigned pk = ymm[((size_t)d*NBLK + blk)*16 + j];
    const float a = ab[AB_A3 + d], e = ab[AB_E3 + d];
    const float mx = bs2f((unsigned short)(pk & 0xFFFF));
    const float mn = bs2f((unsigned short)(pk >> 16));
    const float v = (a >= 0.f) ? mx : mn;
    out[idx] = fmaxf(__fmaf_rn(a, v, e), 0.f);
}

// ---------------------------------------------------------------------------
extern "C" void kernel_launch(void* const* d_in, const int* in_sizes, int n_in,
                              void* d_out, int out_size, void* d_ws, size_t ws_size,
                              hipStream_t stream) {
    (void)in_sizes; (void)n_in; (void)out_size; (void)ws_size;
    const float* x   = (const float*)d_in[0];
    const float* W1  = (const float*)d_in[1];
    const float* b1  = (const float*)d_in[2];
    const float* g1  = (const float*)d_in[3];
    const float* be1 = (const float*)d_in[4];
    const float* W2  = (const float*)d_in[5];
    const float* b2  = (const float*)d_in[6];
    const float* g2  = (const float*)d_in[7];
    const float* be2 = (const float*)d_in[8];
    const float* W3  = (const float*)d_in[9];
    const float* b3  = (const float*)d_in[10];
    const float* g3  = (const float*)d_in[11];
    const float* be3 = (const float*)d_in[12];

    float*  out = (float*)d_out;
    char*   ws  = (char*)d_ws;
    float*          g   = (float*)(ws + OFF_G);
    unsigned short* y2t = (unsigned short*)(ws + OFF_Y2B);
    double*         st  = (double*)(ws + OFF_STATS);
    float*          ab  = (float*)(ws + OFF_AB);
    float*          kp  = (float*)(ws + OFF_KPART);
    unsigned*       ymm = (unsigned*)(ws + OFF_YMM);

    knn_group_kernel<<<dim3(128, B_), 1024, 0, stream>>>(x, g, kp, st);
    finalize1_kernel<<<1, 1024, 0, stream>>>(kp, W1, b1, g1, be1, ab);
    conv_kernel<0,0><<<NBLK, 256, 0, stream>>>(g, nullptr, W2, ab, b2, y2t, nullptr, st, I_S2);
    finalize23_kernel<<<1, 128, 0, stream>>>(st, I_S2, g2, be2, ab, AB_A2);
    conv_kernel<1,3><<<NBLK, 256, 0, stream>>>(nullptr, y2t, W3, ab, b3, nullptr, ymm, st, I_S3);
    finalize23_kernel<<<1, 128, 0, stream>>>(st, I_S3, g3, be3, ab, AB_A3);
    bn3max_kernel<<<(B_*DIM*N_)/256, 256, 0, stream>>>(ymm, ab, out);
}

// Round 17
// 153.524 us; speedup vs baseline: 2.5125x; 1.2671x over previous
//
#include <hip/hip_runtime.h>
#include <hip/hip_bf16.h>
#include <math.h>

// ---------------------------------------------------------------------------
// FeatureNet (DGCNN edge-conv block), MI355X / gfx950, round 17.
//
// Round-17 = round-16 pipeline with conv blocks restructured 256->512 threads
// (8 waves x 16d instead of 4 waves x 32d, same 128x128 tile, same swizzles).
// Rationale: convs are latency-bound (MfmaUtil 4.5%, VALU 26%, HBM 15%,
// Occ 19.5%); halving per-wave ownership doubles resident waves per block
// (LDS still caps 4 blocks/CU -> 32 waves instead of 16).
// ---------------------------------------------------------------------------

#define B_   16
#define N_   2048
#define KNN  8
#define DIM  128
#define P_   (B_*N_*KNN)   // 262144
#define CAP  128
#define NBLK 2048          // conv blocks (128 p each)

typedef __attribute__((ext_vector_type(8))) short bf16x8;
typedef __attribute__((ext_vector_type(4))) short bf16x4;
typedef __attribute__((ext_vector_type(4))) float f32x4;

// ws layout (bytes)
#define OFF_G     0ull
#define SZ_G      ((size_t)3*P_*4)
#define OFF_Y2B   (OFF_G + SZ_G)
#define SZ_Y2B    ((size_t)DIM*P_*2)           // 67,108,864  (y2t[p][c])
#define OFF_STATS (OFF_Y2B + SZ_Y2B)
#define N_STATS   4112
#define SZ_STATS  ((size_t)N_STATS*8)
#define OFF_AB    (OFF_STATS + SZ_STATS)
#define SZ_AB     4096ull
#define OFF_KPART (OFF_AB + SZ_AB)
#define NKBLK     2048
#define SZ_KPART  ((size_t)9*NKBLK*4)
#define OFF_YMM   (OFF_KPART + SZ_KPART)
#define SZ_YMM    ((size_t)DIM*NBLK*16*4)      // packed u32 (max,min)

// stats (f64) indices
#define I_S2   16
#define I_S3   (16 + 8*256)
#define NBANK  8

// ab (float) layout
#define AB_W1F 0
#define AB_A2  512
#define AB_E2  640
#define AB_A3  768
#define AB_E3  896

// DPP ctrl codes (all source lanes valid)
#define DPP_XOR1   0xB1    // quad_perm [1,0,3,2]
#define DPP_XOR2   0x4E    // quad_perm [2,3,0,1]
#define DPP_HALFM  0x141   // row_half_mirror: lane ^ 7
#define DPP_MIRROR 0x140   // row_mirror: lane ^ 15

template<int C>
__device__ __forceinline__ float dppf(float v) {
    return __int_as_float(__builtin_amdgcn_update_dpp(
        __float_as_int(v), __float_as_int(v), C, 0xF, 0xF, false));
}

__device__ __forceinline__ void atomAddD(double* p, double v) {
    __hip_atomic_fetch_add(p, v, __ATOMIC_RELAXED, __HIP_MEMORY_SCOPE_AGENT);
}
__device__ __forceinline__ unsigned short f2bs(float f) {
    const unsigned b = __float_as_uint(f);
    return (unsigned short)((b + 0x7FFFu + ((b >> 16) & 1u)) >> 16);   // RNE
}
__device__ __forceinline__ float bs2f(unsigned short u) {
    return __uint_as_float(((unsigned)u) << 16);
}

// ---------------------------------------------------------------------------
// kNN + grouped offsets + layer-1 moment partials + stats zeroing (r16 proven).
__global__ __launch_bounds__(1024) void knn_group_kernel(
    const float* __restrict__ x, float* __restrict__ g,
    float* __restrict__ kpart, double* __restrict__ st)
{
    __shared__ __align__(16) float4 xs4[N_];
    __shared__ unsigned long long listK[16][CAP];
    __shared__ float spart[16][12];
    const int b   = blockIdx.y;
    const int tid = threadIdx.x;
    const int wv  = tid >> 6;
    const int ln  = tid & 63;
    const int n   = blockIdx.x * 16 + wv;
    const float* xb = x + (size_t)b * 3 * N_;

    if (blockIdx.x == 0 && blockIdx.y == 0)
        for (int i = tid; i < N_STATS; i += 1024) st[i] = 0.0;

    for (int i = tid; i < N_; i += 1024) {
        const float a0 = xb[i], a1 = xb[N_ + i], a2 = xb[2*N_ + i];
        const float sq = __fadd_rn(__fadd_rn(__fmul_rn(a0,a0), __fmul_rn(a1,a1)), __fmul_rn(a2,a2));
        xs4[i] = make_float4(a0, a1, a2, sq);
    }
    __syncthreads();

    const float4 me = xs4[n];
    const float xn0 = me.x, xn1 = me.y, xn2 = me.z, sqn = me.w;

    float dreg[32];
    float lmin = INFINITY;
    #pragma unroll
    for (int i = 0; i < 32; ++i) {
        const float4 q = xs4[ln + 64*i];
        dreg[i] = __fadd_rn(__fmaf_rn(-2.f, __fmaf_rn(xn2, q.z, __fmaf_rn(xn1, q.y, __fmul_rn(xn0, q.x))), sqn), q.w);
        lmin = fminf(lmin, dreg[i]);
    }

    float gm = lmin;
    gm = fminf(gm, __shfl_xor(gm, 1));
    gm = fminf(gm, __shfl_xor(gm, 2));
    gm = fminf(gm, __shfl_xor(gm, 4));
    float Bb = gm;
    Bb = fmaxf(Bb, __shfl_xor(Bb, 8));
    Bb = fmaxf(Bb, __shfl_xor(Bb, 16));
    Bb = fmaxf(Bb, __shfl_xor(Bb, 32));

    unsigned base = 0;
    #pragma unroll
    for (int i = 0; i < 32; ++i) {
        const bool pred = (dreg[i] <= Bb);
        const unsigned long long mk = __ballot(pred);
        if (pred) {
            const unsigned pos = base + (unsigned)__popcll(mk & ((1ull << ln) - 1ull));
            if (pos < CAP) {
                const unsigned u = __float_as_uint(dreg[i]);
                const unsigned od = u ^ ((unsigned)(((int)u) >> 31) | 0x80000000u);
                listK[wv][pos] = (((unsigned long long)od) << 32) | (unsigned)(ln + 64*i);
            }
        }
        base += (unsigned)__popcll(mk);
    }
    const int cnt = (base < CAP) ? (int)base : CAP;

    int myi = 0;
    if (cnt <= 64) {
        unsigned long long K = (ln < cnt) ? listK[wv][ln] : ~0ull;
        #pragma unroll
        for (int k = 2; k <= 64; k <<= 1) {
            #pragma unroll
            for (int j = k >> 1; j >= 1; j >>= 1) {
                const unsigned long long o = __shfl_xor(K, j);
                const bool takeMin = (((ln & j) == 0) == ((ln & k) == 0));
                const bool oLess = (o < K);
                if (takeMin ? oLess : !oLess) K = o;
            }
        }
        myi = (int)(unsigned)K;
    } else {
        unsigned long long K0 = (ln < cnt)      ? listK[wv][ln]      : ~0ull;
        unsigned long long K1 = (ln + 64 < cnt) ? listK[wv][ln + 64] : ~0ull;
        #pragma unroll
        for (int sel = 0; sel < 8; ++sel) {
            unsigned long long p = (K1 < K0) ? K1 : K0;
            #pragma unroll
            for (int m = 1; m < 64; m <<= 1) {
                const unsigned long long o = __shfl_xor(p, m);
                if (o < p) p = o;
            }
            if (ln == sel) myi = (int)(unsigned)p;
            if (K0 == p) K0 = ~0ull;
            if (K1 == p) K1 = ~0ull;
        }
    }

    if (ln < 8) {
        const float4 q = xs4[myi];
        const float g0  = q.x - xn0;
        const float g1v = q.y - xn1;
        const float g2v = q.z - xn2;
        const size_t basep = ((size_t)b*N_ + n) * KNN;
        g[0*P_ + basep + ln] = g0;
        g[1*P_ + basep + ln] = g1v;
        g[2*P_ + basep + ln] = g2v;
        float s0 = g0, s1 = g1v, s2 = g2v;
        float s00 = g0*g0, s01 = g0*g1v, s02 = g0*g2v;
        float s11 = g1v*g1v, s12 = g1v*g2v, s22 = g2v*g2v;
        #pragma unroll
        for (int m = 1; m < 8; m <<= 1) {
            s0 += __shfl_xor(s0, m);  s1 += __shfl_xor(s1, m);  s2 += __shfl_xor(s2, m);
            s00 += __shfl_xor(s00, m); s01 += __shfl_xor(s01, m); s02 += __shfl_xor(s02, m);
            s11 += __shfl_xor(s11, m); s12 += __shfl_xor(s12, m); s22 += __shfl_xor(s22, m);
        }
        if (ln == 0) {
            spart[wv][0] = s0;  spart[wv][1] = s1;  spart[wv][2] = s2;
            spart[wv][3] = s00; spart[wv][4] = s01; spart[wv][5] = s02;
            spart[wv][6] = s11; spart[wv][7] = s12; spart[wv][8] = s22;
        }
    }
    __syncthreads();
    if (tid < 9) {
        float a = 0.f;
        #pragma unroll
        for (int w = 0; w < 16; ++w) a += spart[w][tid];
        kpart[tid*NKBLK + blockIdx.y*128 + blockIdx.x] = a;
    }
}

// ---------------------------------------------------------------------------
__global__ __launch_bounds__(1024) void finalize1_kernel(
    const float* __restrict__ kpart, const float* __restrict__ W1,
    const float* __restrict__ b1, const float* __restrict__ g1,
    const float* __restrict__ be1, float* __restrict__ ab)
{
    __shared__ double S9[9];
    const int tid = threadIdx.x;
    const int w = tid >> 6, l = tid & 63;
    if (w < 9) {
        double a = 0.0;
        #pragma unroll
        for (int i = 0; i < 32; ++i) a += (double)kpart[w*NKBLK + l + 64*i];
        #pragma unroll
        for (int m = 1; m < 64; m <<= 1) a += __shfl_xor(a, m);
        if (l == 0) S9[w] = a;
    }
    __syncthreads();
    if (tid < 128) {
        const int d = tid;
        const double inv = 1.0 / (double)P_;
        const double mu0 = S9[0]*inv, mu1 = S9[1]*inv, mu2 = S9[2]*inv;
        const double c00 = S9[3]*inv - mu0*mu0;
        const double c01 = S9[4]*inv - mu0*mu1;
        const double c02 = S9[5]*inv - mu0*mu2;
        const double c11 = S9[6]*inv - mu1*mu1;
        const double c12 = S9[7]*inv - mu1*mu2;
        const double c22 = S9[8]*inv - mu2*mu2;
        const double w0 = W1[d*3+0], w1 = W1[d*3+1], w2 = W1[d*3+2];
        const double mean = w0*mu0 + w1*mu1 + w2*mu2 + (double)b1[d];
        double var = w0*w0*c00 + w1*w1*c11 + w2*w2*c22
                   + 2.0*(w0*w1*c01 + w0*w2*c02 + w1*w2*c12);
        if (var < 0.0) var = 0.0;
        const double r = 1.0 / sqrt(var + 1e-5);
        const double alpha = (double)g1[d] * r;
        const double beta  = (double)be1[d] - mean*alpha;
        ab[AB_W1F + 4*d + 0] = (float)(alpha * w0);
        ab[AB_W1F + 4*d + 1] = (float)(alpha * w1);
        ab[AB_W1F + 4*d + 2] = (float)(alpha * w2);
        ab[AB_W1F + 4*d + 3] = (float)(alpha * (double)b1[d] + beta);
    }
}

__global__ void finalize23_kernel(
    const double* __restrict__ st, int soff,
    const float* __restrict__ gg, const float* __restrict__ bee,
    float* __restrict__ ab, int aoff)
{
    const int d = threadIdx.x;
    if (d >= DIM) return;
    double s1 = 0.0, s2 = 0.0;
    #pragma unroll
    for (int k = 0; k < NBANK; ++k) {
        s1 += st[soff + k*256 + d];
        s2 += st[soff + k*256 + 128 + d];
    }
    const double inv = 1.0 / (double)P_;
    const double mean = s1 * inv;
    double var = s2 * inv - mean*mean;
    if (var < 0.0) var = 0.0;
    const double r = 1.0 / sqrt(var + 1e-5);
    const double alpha = (double)gg[d] * r;
    ab[aoff + d]       = (float)alpha;
    ab[aoff + 128 + d] = (float)((double)bee[d] - mean*alpha);
}

// ---------------------------------------------------------------------------
// MFMA conv, 512 threads = 8 waves; wave w owns d in [16w, 16w+16).
// Same 128x128 tile, same Ht[p][c] layout + XOR(p&7) octet swizzle as r16.
// SRC 0: H from g via folded W1f (conv2).
// SRC 1: H = relu(a2*y2t+e2), y2t p-major coalesced b128 loads (conv3).
// MODE 0: y2t via LDS transpose (stride 136) + stats.
// MODE 3: stats + per-point max/min packed bf16x2 -> ymm.
template<int SRC, int MODE>
__global__ __launch_bounds__(512) void conv_kernel(
    const float* __restrict__ gsrc, const unsigned short* __restrict__ ybsrc,
    const float* __restrict__ Wf, const float* __restrict__ ab,
    const float* __restrict__ bias, unsigned short* __restrict__ ybdst,
    unsigned* __restrict__ ymm, double* __restrict__ stats, int statoff)
{
    __shared__ __align__(16) short Hs[128*136];
    const int tid = threadIdx.x;          // 0..511
    const int p0g = blockIdx.x * 128;
    const int w  = tid >> 6;              // 0..7
    const int ln = tid & 63;
    const int lg = ln >> 4, lr = ln & 15;

    // A-frags: wave w covers d rows [16w, 16w+16)
    bf16x8 afrag[4];
    #pragma unroll
    for (int ks = 0; ks < 4; ++ks) {
        const float* wr = &Wf[(size_t)(16*w + lr)*DIM + (4*ks + lg)*8];
        const float4 a4 = *(const float4*)wr;
        const float4 b4 = *(const float4*)(wr + 4);
        bf16x8 f;
        f[0]=(short)f2bs(a4.x); f[1]=(short)f2bs(a4.y); f[2]=(short)f2bs(a4.z); f[3]=(short)f2bs(a4.w);
        f[4]=(short)f2bs(b4.x); f[5]=(short)f2bs(b4.y); f[6]=(short)f2bs(b4.z); f[7]=(short)f2bs(b4.w);
        afrag[ks] = f;
    }

    if constexpr (SRC == 0) {
        const int sp = tid & 127;         // row (p)
        const int ob = tid >> 7;          // 0..3
        const float gx = gsrc[0*P_ + p0g + sp];
        const float gy = gsrc[1*P_ + p0g + sp];
        const float gz = gsrc[2*P_ + p0g + sp];
        #pragma unroll
        for (int it = 0; it < 4; ++it) {
            const int o = ob + 4*it;
            bf16x8 hv;
            #pragma unroll
            for (int j = 0; j < 8; ++j) {
                const int c = 8*o + j;
                const float4 wf = *(const float4*)&ab[AB_W1F + 4*c];
                const float h = fmaxf(__fmaf_rn(wf.x, gx, __fmaf_rn(wf.y, gy, __fmaf_rn(wf.z, gz, wf.w))), 0.f);
                hv[j] = (short)f2bs(h);
            }
            *(bf16x8*)&Hs[sp*128 + ((o ^ (sp & 7)) * 8)] = hv;
        }
    } else {
        const int myoct = tid & 15;
        const float4 aLo = *(const float4*)&ab[AB_A2 + myoct*8];
        const float4 aHi = *(const float4*)&ab[AB_A2 + myoct*8 + 4];
        const float4 eLo = *(const float4*)&ab[AB_E2 + myoct*8];
        const float4 eHi = *(const float4*)&ab[AB_E2 + myoct*8 + 4];
        const float av[8] = {aLo.x,aLo.y,aLo.z,aLo.w,aHi.x,aHi.y,aHi.z,aHi.w};
        const float ev[8] = {eLo.x,eLo.y,eLo.z,eLo.w,eHi.x,eHi.y,eHi.z,eHi.w};
        #pragma unroll
        for (int it = 0; it < 4; ++it) {
            const int p = it*32 + (tid >> 4);   // 0..127
            const bf16x8 raw = *(const bf16x8*)&ybsrc[(size_t)(p0g + p)*128 + myoct*8];
            bf16x8 hv;
            #pragma unroll
            for (int j = 0; j < 8; ++j) {
                const float v = bs2f((unsigned short)raw[j]);
                hv[j] = (short)f2bs(fmaxf(__fmaf_rn(av[j], v, ev[j]), 0.f));
            }
            *(bf16x8*)&Hs[p*128 + ((myoct ^ (p & 7)) * 8)] = hv;
        }
    }
    __syncthreads();

    f32x4 acc[8];
    #pragma unroll
    for (int j = 0; j < 8; ++j) acc[j] = (f32x4){0.f, 0.f, 0.f, 0.f};

    #pragma unroll
    for (int ks = 0; ks < 4; ++ks) {
        #pragma unroll
        for (int pt = 0; pt < 8; ++pt) {
            const int p = 16*pt + lr;
            const bf16x8 bf = *(const bf16x8*)&Hs[p*128 + (((4*ks + lg) ^ (lr & 7)) * 8)];
            acc[pt] = __builtin_amdgcn_mfma_f32_16x16x32_bf16(afrag[ks], bf, acc[pt], 0, 0, 0);
        }
    }

    // ---- stats + MODE 3 packed minmax, reductions on DPP
    const int bank = blockIdx.x & (NBANK-1);
    #pragma unroll
    for (int r = 0; r < 4; ++r) {
        const int d = 16*w + 4*lg + r;
        const float bb = bias[d];
        float v[8];
        #pragma unroll
        for (int pt = 0; pt < 8; ++pt) v[pt] = acc[pt][r] + bb;

        float s1 = ((v[0]+v[1])+(v[2]+v[3])) + ((v[4]+v[5])+(v[6]+v[7]));
        float s2 = ((v[0]*v[0]+v[1]*v[1])+(v[2]*v[2]+v[3]*v[3]))
                 + ((v[4]*v[4]+v[5]*v[5])+(v[6]*v[6]+v[7]*v[7]));
        s1 += dppf<DPP_XOR1>(s1);  s2 += dppf<DPP_XOR1>(s2);
        s1 += dppf<DPP_XOR2>(s1);  s2 += dppf<DPP_XOR2>(s2);
        s1 += dppf<DPP_HALFM>(s1); s2 += dppf<DPP_HALFM>(s2);
        s1 += dppf<DPP_MIRROR>(s1); s2 += dppf<DPP_MIRROR>(s2);
        if (lr == 0) {
            atomAddD(&stats[statoff + bank*256 + d], (double)s1);
            atomAddD(&stats[statoff + bank*256 + 128 + d], (double)s2);
        }

        if constexpr (MODE == 3) {
            #pragma unroll
            for (int pt = 0; pt < 8; ++pt) {
                float mx = v[pt], mn = v[pt];
                mx = fmaxf(mx, dppf<DPP_XOR1>(mx));  mn = fminf(mn, dppf<DPP_XOR1>(mn));
                mx = fmaxf(mx, dppf<DPP_XOR2>(mx));  mn = fminf(mn, dppf<DPP_XOR2>(mn));
                mx = fmaxf(mx, dppf<DPP_HALFM>(mx)); mn = fminf(mn, dppf<DPP_HALFM>(mn));
                if ((lr & 7) == 0) {
                    const int slot = 2*pt + (lr >> 3);
                    ymm[((size_t)d*NBLK + blockIdx.x)*16 + slot] =
                        (unsigned)f2bs(mx) | ((unsigned)f2bs(mn) << 16);
                }
            }
        }
    }

    if constexpr (MODE == 0) {
        // ---- LDS transpose -> fully coalesced p-major stores
        __syncthreads();   // all waves done reading Hs (B-frags)
        const int d0 = 16*w + 4*lg;
        const float4 b4 = *(const float4*)&bias[d0];
        #pragma unroll
        for (int pt = 0; pt < 8; ++pt) {
            const int p = 16*pt + lr;
            bf16x4 pk;
            pk[0] = (short)f2bs(acc[pt][0] + b4.x);
            pk[1] = (short)f2bs(acc[pt][1] + b4.y);
            pk[2] = (short)f2bs(acc[pt][2] + b4.z);
            pk[3] = (short)f2bs(acc[pt][3] + b4.w);
            *(bf16x4*)&Hs[p*136 + d0] = pk;
        }
        __syncthreads();
        #pragma unroll
        for (int it = 0; it < 4; ++it) {
            const int f = it*512 + tid;
            const int row = f >> 4, ch = f & 15;
            const bf16x8 vv = *(const bf16x8*)&Hs[row*136 + ch*8];
            *(bf16x8*)&ybdst[(size_t)(p0g + row)*128 + ch*8] = vv;
        }
    }
}

// ---------------------------------------------------------------------------
// Epilogue: out[b,d,n] = relu(a3*(a3>=0 ? max_k : min_k) + e3), packed ymm.
__global__ __launch_bounds__(256) void bn3max_kernel(
    const unsigned* __restrict__ ymm, const float* __restrict__ ab, float* __restrict__ out)
{
    const int idx = blockIdx.x*256 + threadIdx.x;
    const int n = idx & (N_-1);
    const int d = (idx >> 11) & (DIM-1);
    const int b = idx >> 18;
    const int pt  = b*N_ + n;
    const int blk = pt >> 4;
    const int j   = pt & 15;
    const unsigned pk = ymm[((size_t)d*NBLK + blk)*16 + j];
    const float a = ab[AB_A3 + d], e = ab[AB_E3 + d];
    const float mx = bs2f((unsigned short)(pk & 0xFFFF));
    const float mn = bs2f((unsigned short)(pk >> 16));
    const float v = (a >= 0.f) ? mx : mn;
    out[idx] = fmaxf(__fmaf_rn(a, v, e), 0.f);
}

// ---------------------------------------------------------------------------
extern "C" void kernel_launch(void* const* d_in, const int* in_sizes, int n_in,
                              void* d_out, int out_size, void* d_ws, size_t ws_size,
                              hipStream_t stream) {
    (void)in_sizes; (void)n_in; (void)out_size; (void)ws_size;
    const float* x   = (const float*)d_in[0];
    const float* W1  = (const float*)d_in[1];
    const float* b1  = (const float*)d_in[2];
    const float* g1  = (const float*)d_in[3];
    const float* be1 = (const float*)d_in[4];
    const float* W2  = (const float*)d_in[5];
    const float* b2  = (const float*)d_in[6];
    const float* g2  = (const float*)d_in[7];
    const float* be2 = (const float*)d_in[8];
    const float* W3  = (const float*)d_in[9];
    const float* b3  = (const float*)d_in[10];
    const float* g3  = (const float*)d_in[11];
    const float* be3 = (const float*)d_in[12];

    float*  out = (float*)d_out;
    char*   ws  = (char*)d_ws;
    float*          g   = (float*)(ws + OFF_G);
    unsigned short* y2t = (unsigned short*)(ws + OFF_Y2B);
    double*         st  = (double*)(ws + OFF_STATS);
    float*          ab  = (float*)(ws + OFF_AB);
    float*          kp  = (float*)(ws + OFF_KPART);
    unsigned*       ymm = (unsigned*)(ws + OFF_YMM);

    knn_group_kernel<<<dim3(128, B_), 1024, 0, stream>>>(x, g, kp, st);
    finalize1_kernel<<<1, 1024, 0, stream>>>(kp, W1, b1, g1, be1, ab);
    conv_kernel<0,0><<<NBLK, 512, 0, stream>>>(g, nullptr, W2, ab, b2, y2t, nullptr, st, I_S2);
    finalize23_kernel<<<1, 128, 0, stream>>>(st, I_S2, g2, be2, ab, AB_A2);
    conv_kernel<1,3><<<NBLK, 512, 0, stream>>>(nullptr, y2t, W3, ab, b3, nullptr, ymm, st, I_S3);
    finalize23_kernel<<<1, 128, 0, stream>>>(st, I_S3, g3, be3, ab, AB_A3);
    bn3max_kernel<<<(B_*DIM*N_)/256, 256, 0, stream>>>(ymm, ab, out);
}